// Round 18
// baseline (47.123 us; speedup 1.0000x reference)
//
#include <hip/hip_runtime.h>

// Problem constants
#define NTOK   (64 * 4096)   // B*S tokens
#define DDIM   64            // num_dim
#define NCLUST 256           // num_clusters
#define NFEAT  7             // continuous features
#define RT     2             // row-tiles of 16 tokens per wave
#define BLK    256           // threads per block (4 waves)
// tokens per block = 4 waves * RT*16 = 128 ; grid = 2048

typedef _Float16 f16x8 __attribute__((ext_vector_type(8)));
typedef float    f32x4 __attribute__((ext_vector_type(4)));

// -2 * (log2 e)^2 : folds softmax exp into exp2 and the -2 dot factor
#define KNEG2K (-4.1627379924399795f)

// ws layout: [0, 2048) float pre[512] = c2[256] ++ cw[256]
//            [2048, 2048+32768) _Float16 cent_hswz[256*64]   (f16-hi ONLY)
// cent_hswz row c: 8 chunks of 8 halves (16B); chunk j = f16(cent[c][j*8..+8))
// stored at chunk position (j ^ (c&7))  [XOR swizzle; 0 conflicts measured R13]
// LDS: s_cent[256*64] halves (32768B) ++ s_pre[512] floats (2048B)

// ---- kernel 1a: per-cluster c2 / cw (verified R3..R17, verbatim) ----
__global__ __launch_bounds__(NCLUST) void precompute_kernel(
    const float* __restrict__ centroids,
    const float* __restrict__ W2,
    float* __restrict__ pre) {
  const int c = threadIdx.x;
  const float4* cp = (const float4*)(centroids + c * DDIM);
  const float4* wp = (const float4*)W2;
  float c2a = 0.f, c2b = 0.f, cwa = 0.f, cwb = 0.f;
#pragma unroll
  for (int i = 0; i < DDIM / 4; i += 2) {
    float4 v0 = cp[i], v1 = cp[i + 1];
    float4 w0 = wp[i], w1 = wp[i + 1];
    c2a = fmaf(v0.x, v0.x, fmaf(v0.y, v0.y, fmaf(v0.z, v0.z, fmaf(v0.w, v0.w, c2a))));
    c2b = fmaf(v1.x, v1.x, fmaf(v1.y, v1.y, fmaf(v1.z, v1.z, fmaf(v1.w, v1.w, c2b))));
    cwa = fmaf(v0.x, w0.x, fmaf(v0.y, w0.y, fmaf(v0.z, w0.z, fmaf(v0.w, w0.w, cwa))));
    cwb = fmaf(v1.x, w1.x, fmaf(v1.y, w1.y, fmaf(v1.z, w1.z, fmaf(v1.w, w1.w, cwb))));
  }
  pre[c] = c2a + c2b;
  pre[NCLUST + c] = cwa + cwb;
}

// ---- kernel 1b: f16-hi split -> XOR-swizzled chunk layout (verified R13) ----
__global__ __launch_bounds__(256) void split_kernel(
    const float* __restrict__ centroids,
    _Float16* __restrict__ cent_hswz) {
  const int tid = blockIdx.x * 256 + threadIdx.x;  // 0..2047
  const int c = tid >> 3;
  const int j = tid & 7;
  const int d0 = j * 8;
  f16x8 v;
#pragma unroll
  for (int i = 0; i < 8; ++i)
    v[i] = (_Float16)centroids[c * DDIM + d0 + i];
  *(f16x8*)&cent_hswz[c * 64 + (j ^ (c & 7)) * 8] = v;
}

// ---- kernel 2: fused main kernel ----
// RT=2, 4 waves/block (256 thr), wave = 32 tokens x 256 clusters; grid 2048.
// R18: __launch_bounds__ 2nd arg acts as BLOCKS/CU residency cap (R8/R9/R16/
// R17 evidence: measured occupancy ~= 0.7 x declared cap). R17's (256,3)
// self-capped at 3 blocks/CU; LDS (4x34.8KB=139<=160KB) and VGPR (76<=128)
// both allow 4. (256,4) lifts residency 12 -> 16 waves/CU.
__global__ __launch_bounds__(BLK, 4) void main_kernel(
    const float* __restrict__ x,
    const float* __restrict__ W_embed,
    const float* __restrict__ b_embed,
    const float* __restrict__ emb_table,
    const float* __restrict__ b2,
    const float* __restrict__ pre,
    const _Float16* __restrict__ cent_hswz,
    float* __restrict__ out) {
  extern __shared__ _Float16 s_cent[];             // 256*64 halves = 32768 B
  float* s_pre = (float*)(s_cent + NCLUST * 64);   // 512 floats = 2048 B

  const int tid  = threadIdx.x;
  const int lane = tid & 63;
  const int wv   = tid >> 6;          // wave in block: 0..3
  const int col  = lane & 15;         // A-row (token) / B,C-col (cluster)
  const int g    = lane >> 4;         // k-group (0..3)
  const int tokBase = blockIdx.x * (4 * 16 * RT) + wv * (16 * RT);

  // ---- stage cent_hswz (32KB) + pre (2KB) -> LDS ----
  {
    const float4* gsrc = (const float4*)cent_hswz;   // 2048 float4
    float4* ldst = (float4*)s_cent;
#pragma unroll
    for (int i = 0; i < 8; ++i)
      ldst[tid + BLK * i] = gsrc[tid + BLK * i];
    s_pre[tid] = pre[tid];
    s_pre[tid + 256] = pre[tid + 256];
  }

  // ---- b_embed fragment (token-independent) ----
  const float4* br = (const float4*)b_embed;
  const float4 q0 = br[2 * g], q1 = br[2 * g + 1];
  const float4 q2 = br[8 + 2 * g], q3 = br[8 + 2 * g + 1];

  // ---- prologue: h[rt][0..7]=dims[g*8..+8), h[rt][8..15]=dims[32+g*8..+8) ----
  float h[RT][16];
  float xf[RT][NFEAT];
#pragma unroll
  for (int rt = 0; rt < RT; ++rt) {
    const int tok = tokBase + rt * 16 + col;
    const float4* xp = (const float4*)(x + (size_t)tok * 8);
    const float4 xa = xp[0], xb = xp[1];
    xf[rt][0] = xa.x; xf[rt][1] = xa.y; xf[rt][2] = xa.z; xf[rt][3] = xa.w;
    xf[rt][4] = xb.x; xf[rt][5] = xb.y; xf[rt][6] = xb.z;
    const int idx = (int)xb.w;
    const float4* er = (const float4*)(emb_table + (size_t)idx * DDIM);
    const float4 e0 = er[2 * g], e1 = er[2 * g + 1];
    const float4 e2 = er[8 + 2 * g], e3 = er[8 + 2 * g + 1];
    h[rt][0]  = e0.x + q0.x; h[rt][1]  = e0.y + q0.y;
    h[rt][2]  = e0.z + q0.z; h[rt][3]  = e0.w + q0.w;
    h[rt][4]  = e1.x + q1.x; h[rt][5]  = e1.y + q1.y;
    h[rt][6]  = e1.z + q1.z; h[rt][7]  = e1.w + q1.w;
    h[rt][8]  = e2.x + q2.x; h[rt][9]  = e2.y + q2.y;
    h[rt][10] = e2.z + q2.z; h[rt][11] = e2.w + q2.w;
    h[rt][12] = e3.x + q3.x; h[rt][13] = e3.y + q3.y;
    h[rt][14] = e3.z + q3.z; h[rt][15] = e3.w + q3.w;
  }
  // W_embed: f outer (W fragment loaded once), rt inner
#pragma unroll
  for (int f = 0; f < NFEAT; ++f) {
    const float4* wr = (const float4*)(W_embed + f * DDIM);
    const float4 w0 = wr[2 * g], w1 = wr[2 * g + 1];
    const float4 w2 = wr[8 + 2 * g], w3 = wr[8 + 2 * g + 1];
#pragma unroll
    for (int rt = 0; rt < RT; ++rt) {
      const float xv = xf[rt][f];
      h[rt][0]  = fmaf(xv, w0.x, h[rt][0]);  h[rt][1]  = fmaf(xv, w0.y, h[rt][1]);
      h[rt][2]  = fmaf(xv, w0.z, h[rt][2]);  h[rt][3]  = fmaf(xv, w0.w, h[rt][3]);
      h[rt][4]  = fmaf(xv, w1.x, h[rt][4]);  h[rt][5]  = fmaf(xv, w1.y, h[rt][5]);
      h[rt][6]  = fmaf(xv, w1.z, h[rt][6]);  h[rt][7]  = fmaf(xv, w1.w, h[rt][7]);
      h[rt][8]  = fmaf(xv, w2.x, h[rt][8]);  h[rt][9]  = fmaf(xv, w2.y, h[rt][9]);
      h[rt][10] = fmaf(xv, w2.z, h[rt][10]); h[rt][11] = fmaf(xv, w2.w, h[rt][11]);
      h[rt][12] = fmaf(xv, w3.x, h[rt][12]); h[rt][13] = fmaf(xv, w3.y, h[rt][13]);
      h[rt][14] = fmaf(xv, w3.z, h[rt][14]); h[rt][15] = fmaf(xv, w3.w, h[rt][15]);
    }
  }

  // ---- per-rt: h2 reduce (pre-scaled by -0.5) + f16 hi/lo split, NAMED frags ----
  f16x8 ah0_0, al0_0, ah1_0, al1_0; float nhb_0[4];
  f16x8 ah0_1, al0_1, ah1_1, al1_1; float nhb_1[4];

#define SPLIT_RT(RTI, AH0, AL0, AH1, AL1, NHB) do {                         \
    float ptl = 0.f;                                                        \
    _Pragma("unroll") for (int i = 0; i < 8; ++i) {                         \
      ptl = fmaf(h[RTI][i], h[RTI][i], ptl);                                \
      ptl = fmaf(h[RTI][8 + i], h[RTI][8 + i], ptl);                        \
    }                                                                       \
    ptl += __shfl_xor(ptl, 16);                                             \
    ptl += __shfl_xor(ptl, 32);                                             \
    ptl *= -0.5f;                                                           \
    _Pragma("unroll") for (int r = 0; r < 4; ++r)                           \
      NHB[r] = __shfl(ptl, g * 4 + r);                                      \
    _Pragma("unroll") for (int i = 0; i < 8; ++i) {                         \
      _Float16 t0 = (_Float16)h[RTI][i];                                    \
      AH0[i] = t0; AL0[i] = (_Float16)(h[RTI][i] - (float)t0);              \
      _Float16 t1 = (_Float16)h[RTI][8 + i];                                \
      AH1[i] = t1; AL1[i] = (_Float16)(h[RTI][8 + i] - (float)t1);          \
    }                                                                       \
  } while (0)

  SPLIT_RT(0, ah0_0, al0_0, ah1_0, al1_0, nhb_0);
  SPLIT_RT(1, ah0_1, al0_1, ah1_1, al1_1, nhb_1);
#undef SPLIT_RT

  __syncthreads();   // LDS stage complete

  // ---- loop-invariant LDS addressing (sw = (t*16+col)&7 = col&7) ----
  const int sw  = col & 7;
  const _Float16* base0 = s_cent + col * 64 + ((g) ^ sw) * 8;       // chunk a
  const _Float16* base1 = s_cent + col * 64 + ((4 + g) ^ sw) * 8;   // chunk b
  const float* pc2 = s_pre + col;          // c2[t*16+col] at +t*64B (LDS)
  const float* pcw = s_pre + NCLUST + col; // cw[...]

  float ss_0[4] = {0.f, 0.f, 0.f, 0.f}, ww_0[4] = {0.f, 0.f, 0.f, 0.f};
  float ss_1[4] = {0.f, 0.f, 0.f, 0.f}, ww_1[4] = {0.f, 0.f, 0.f, 0.f};

#pragma unroll 2
  for (int t = 0; t < 16; ++t) {
    const f16x8 bh0 = *(const f16x8*)(base0 + t * 1024);   // 16 clusters*64 halves
    const f16x8 bh1 = *(const f16x8*)(base1 + t * 1024);
    const float c2c = pc2[t * 16];
    const float cwc = pcw[t * 16];

#define DO_RT(AH0, AL0, AH1, AL1, NHB, SS, WW) do {                         \
    f32x4 hh;                                                               \
    hh[0] = fmaf(-0.5f, c2c, NHB[0]);                                       \
    hh[1] = fmaf(-0.5f, c2c, NHB[1]);                                       \
    hh[2] = fmaf(-0.5f, c2c, NHB[2]);                                       \
    hh[3] = fmaf(-0.5f, c2c, NHB[3]);                                       \
    f32x4 lh = {0.f, 0.f, 0.f, 0.f};                                        \
    hh = __builtin_amdgcn_mfma_f32_16x16x32_f16(AH0, bh0, hh, 0, 0, 0);     \
    lh = __builtin_amdgcn_mfma_f32_16x16x32_f16(AL0, bh0, lh, 0, 0, 0);     \
    hh = __builtin_amdgcn_mfma_f32_16x16x32_f16(AH1, bh1, hh, 0, 0, 0);     \
    lh = __builtin_amdgcn_mfma_f32_16x16x32_f16(AL1, bh1, lh, 0, 0, 0);     \
    _Pragma("unroll") for (int r = 0; r < 4; ++r) {                         \
      const float m = hh[r] + lh[r];            /* h.c_hi - (h2+c2)/2 */    \
      const float d2s = fmaxf(m * KNEG2K, 0.f); /* (dist*log2e)^2 */        \
      const float dsc = __builtin_amdgcn_sqrtf(d2s);   /* v_sqrt_f32 */     \
      const float e = __builtin_amdgcn_exp2f(-dsc);    /* v_exp_f32 */      \
      SS[r] += e;                                                           \
      WW[r] = fmaf(e, cwc, WW[r]);                                          \
    }                                                                       \
  } while (0)

    DO_RT(ah0_0, al0_0, ah1_0, al1_0, nhb_0, ss_0, ww_0);
    DO_RT(ah0_1, al0_1, ah1_1, al1_1, nhb_1, ss_1, ww_1);
#undef DO_RT
  }

  // ---- reduce over the 16 cluster-lanes, store 32 tokens per wave ----
  const float b2v = b2[0];
#define STORE_RT(RTI, SS, WW) do {                                          \
    _Pragma("unroll") for (int r = 0; r < 4; ++r) {                         \
      float s = SS[r], w = WW[r];                                           \
      s += __shfl_xor(s, 1); w += __shfl_xor(w, 1);                         \
      s += __shfl_xor(s, 2); w += __shfl_xor(w, 2);                         \
      s += __shfl_xor(s, 4); w += __shfl_xor(w, 4);                         \
      s += __shfl_xor(s, 8); w += __shfl_xor(w, 8);                         \
      if (col == 0)                                                         \
        out[tokBase + (RTI) * 16 + g * 4 + r] =                             \
            w * __builtin_amdgcn_rcpf(s) * 0.125f + b2v;                    \
    }                                                                       \
  } while (0)

  STORE_RT(0, ss_0, ww_0);
  STORE_RT(1, ss_1, ww_1);
#undef STORE_RT
}

extern "C" void kernel_launch(void* const* d_in, const int* in_sizes, int n_in,
                              void* d_out, int out_size, void* d_ws, size_t ws_size,
                              hipStream_t stream) {
  const float* x         = (const float*)d_in[0];
  const float* W_embed   = (const float*)d_in[1];
  const float* b_embed   = (const float*)d_in[2];
  const float* emb_table = (const float*)d_in[3];
  const float* centroids = (const float*)d_in[4];
  const float* W2        = (const float*)d_in[5];
  const float* b2        = (const float*)d_in[6];
  float* out = (float*)d_out;

  float* pre = (float*)d_ws;                               // 512 floats
  _Float16* cent_hswz = (_Float16*)((char*)d_ws + 2048);   // 256*64 f16

  precompute_kernel<<<1, NCLUST, 0, stream>>>(centroids, W2, pre);
  split_kernel<<<(NCLUST * 8) / 256, 256, 0, stream>>>(centroids, cent_hswz);
  const int tokPerBlk = 4 * 16 * RT;  // 128
  main_kernel<<<NTOK / tokPerBlk, BLK, 32768 + 2048, stream>>>(
      x, W_embed, b_embed, emb_table, b2, pre, cent_hswz, out);
}

// Round 19
// 44.877 us; speedup vs baseline: 1.0500x; 1.0500x over previous
//
#include <hip/hip_runtime.h>

// Problem constants
#define NTOK   (64 * 4096)   // B*S tokens
#define DDIM   64            // num_dim
#define NCLUST 256           // num_clusters
#define NFEAT  7             // continuous features
#define RT     2             // row-tiles of 16 tokens per wave
#define BLK    256           // threads per block (4 waves)
// tokens per block = 4 waves * RT*16 = 128 ; grid = 2048

typedef _Float16 f16x8 __attribute__((ext_vector_type(8)));
typedef float    f32x4 __attribute__((ext_vector_type(4)));

// -2 * (log2 e)^2 : folds softmax exp into exp2 and the -2 dot factor
#define KNEG2K (-4.1627379924399795f)

// ws layout: [0, 2048) float pre[512] = c2[256] ++ cw[256]
//            [2048, 2048+32768) _Float16 cent_hswz[256*64]   (f16-hi ONLY)
// cent_hswz row c: 8 chunks of 8 halves (16B); chunk j = f16(cent[c][j*8..+8))
// stored at chunk position (j ^ (c&7))  [XOR swizzle; 0 conflicts measured R13]
// LDS: s_cent[256*64] halves (32768B) ++ s_pre[512] floats (2048B)
// R19: A-side also f16-hi only (dot = f16(h).f16(c)). Measured error budget:
// R12 both-sides-hi/lo=1.22e-4, R13 B-hi-only=2.44e-4 (B adds ~1.2e-4);
// A adds same magnitude -> expect ~4e-4 << 9.375e-4 threshold.

// ---- kernel 1a: per-cluster c2 / cw (verified R3..R18, verbatim) ----
__global__ __launch_bounds__(NCLUST) void precompute_kernel(
    const float* __restrict__ centroids,
    const float* __restrict__ W2,
    float* __restrict__ pre) {
  const int c = threadIdx.x;
  const float4* cp = (const float4*)(centroids + c * DDIM);
  const float4* wp = (const float4*)W2;
  float c2a = 0.f, c2b = 0.f, cwa = 0.f, cwb = 0.f;
#pragma unroll
  for (int i = 0; i < DDIM / 4; i += 2) {
    float4 v0 = cp[i], v1 = cp[i + 1];
    float4 w0 = wp[i], w1 = wp[i + 1];
    c2a = fmaf(v0.x, v0.x, fmaf(v0.y, v0.y, fmaf(v0.z, v0.z, fmaf(v0.w, v0.w, c2a))));
    c2b = fmaf(v1.x, v1.x, fmaf(v1.y, v1.y, fmaf(v1.z, v1.z, fmaf(v1.w, v1.w, c2b))));
    cwa = fmaf(v0.x, w0.x, fmaf(v0.y, w0.y, fmaf(v0.z, w0.z, fmaf(v0.w, w0.w, cwa))));
    cwb = fmaf(v1.x, w1.x, fmaf(v1.y, w1.y, fmaf(v1.z, w1.z, fmaf(v1.w, w1.w, cwb))));
  }
  pre[c] = c2a + c2b;
  pre[NCLUST + c] = cwa + cwb;
}

// ---- kernel 1b: f16-hi split -> XOR-swizzled chunk layout (verified R13) ----
__global__ __launch_bounds__(256) void split_kernel(
    const float* __restrict__ centroids,
    _Float16* __restrict__ cent_hswz) {
  const int tid = blockIdx.x * 256 + threadIdx.x;  // 0..2047
  const int c = tid >> 3;
  const int j = tid & 7;
  const int d0 = j * 8;
  f16x8 v;
#pragma unroll
  for (int i = 0; i < 8; ++i)
    v[i] = (_Float16)centroids[c * DDIM + d0 + i];
  *(f16x8*)&cent_hswz[c * 64 + (j ^ (c & 7)) * 8] = v;
}

// ---- kernel 2: fused main kernel ----
// RT=2, 4 waves/block (256 thr), wave = 32 tokens x 256 clusters; grid 2048.
// R19: A-hi-only -> ~62 live regs fits the 64-reg bucket of (256,4) with NO
// spill (R18: 76 live at cap 64 spilled ~2.5MB, gain/loss washed). 2 MFMA
// per rt*tile. 4 blocks/CU = 16 waves/CU residency.
__global__ __launch_bounds__(BLK, 4) void main_kernel(
    const float* __restrict__ x,
    const float* __restrict__ W_embed,
    const float* __restrict__ b_embed,
    const float* __restrict__ emb_table,
    const float* __restrict__ b2,
    const float* __restrict__ pre,
    const _Float16* __restrict__ cent_hswz,
    float* __restrict__ out) {
  extern __shared__ _Float16 s_cent[];             // 256*64 halves = 32768 B
  float* s_pre = (float*)(s_cent + NCLUST * 64);   // 512 floats = 2048 B

  const int tid  = threadIdx.x;
  const int lane = tid & 63;
  const int wv   = tid >> 6;          // wave in block: 0..3
  const int col  = lane & 15;         // A-row (token) / B,C-col (cluster)
  const int g    = lane >> 4;         // k-group (0..3)
  const int tokBase = blockIdx.x * (4 * 16 * RT) + wv * (16 * RT);

  // ---- stage cent_hswz (32KB) + pre (2KB) -> LDS ----
  {
    const float4* gsrc = (const float4*)cent_hswz;   // 2048 float4
    float4* ldst = (float4*)s_cent;
#pragma unroll
    for (int i = 0; i < 8; ++i)
      ldst[tid + BLK * i] = gsrc[tid + BLK * i];
    s_pre[tid] = pre[tid];
    s_pre[tid + 256] = pre[tid + 256];
  }

  // ---- b_embed fragment (token-independent) ----
  const float4* br = (const float4*)b_embed;
  const float4 q0 = br[2 * g], q1 = br[2 * g + 1];
  const float4 q2 = br[8 + 2 * g], q3 = br[8 + 2 * g + 1];

  // ---- prologue: h[rt][0..7]=dims[g*8..+8), h[rt][8..15]=dims[32+g*8..+8) ----
  float h[RT][16];
  float xf[RT][NFEAT];
#pragma unroll
  for (int rt = 0; rt < RT; ++rt) {
    const int tok = tokBase + rt * 16 + col;
    const float4* xp = (const float4*)(x + (size_t)tok * 8);
    const float4 xa = xp[0], xb = xp[1];
    xf[rt][0] = xa.x; xf[rt][1] = xa.y; xf[rt][2] = xa.z; xf[rt][3] = xa.w;
    xf[rt][4] = xb.x; xf[rt][5] = xb.y; xf[rt][6] = xb.z;
    const int idx = (int)xb.w;
    const float4* er = (const float4*)(emb_table + (size_t)idx * DDIM);
    const float4 e0 = er[2 * g], e1 = er[2 * g + 1];
    const float4 e2 = er[8 + 2 * g], e3 = er[8 + 2 * g + 1];
    h[rt][0]  = e0.x + q0.x; h[rt][1]  = e0.y + q0.y;
    h[rt][2]  = e0.z + q0.z; h[rt][3]  = e0.w + q0.w;
    h[rt][4]  = e1.x + q1.x; h[rt][5]  = e1.y + q1.y;
    h[rt][6]  = e1.z + q1.z; h[rt][7]  = e1.w + q1.w;
    h[rt][8]  = e2.x + q2.x; h[rt][9]  = e2.y + q2.y;
    h[rt][10] = e2.z + q2.z; h[rt][11] = e2.w + q2.w;
    h[rt][12] = e3.x + q3.x; h[rt][13] = e3.y + q3.y;
    h[rt][14] = e3.z + q3.z; h[rt][15] = e3.w + q3.w;
  }
  // W_embed: f outer (W fragment loaded once), rt inner
#pragma unroll
  for (int f = 0; f < NFEAT; ++f) {
    const float4* wr = (const float4*)(W_embed + f * DDIM);
    const float4 w0 = wr[2 * g], w1 = wr[2 * g + 1];
    const float4 w2 = wr[8 + 2 * g], w3 = wr[8 + 2 * g + 1];
#pragma unroll
    for (int rt = 0; rt < RT; ++rt) {
      const float xv = xf[rt][f];
      h[rt][0]  = fmaf(xv, w0.x, h[rt][0]);  h[rt][1]  = fmaf(xv, w0.y, h[rt][1]);
      h[rt][2]  = fmaf(xv, w0.z, h[rt][2]);  h[rt][3]  = fmaf(xv, w0.w, h[rt][3]);
      h[rt][4]  = fmaf(xv, w1.x, h[rt][4]);  h[rt][5]  = fmaf(xv, w1.y, h[rt][5]);
      h[rt][6]  = fmaf(xv, w1.z, h[rt][6]);  h[rt][7]  = fmaf(xv, w1.w, h[rt][7]);
      h[rt][8]  = fmaf(xv, w2.x, h[rt][8]);  h[rt][9]  = fmaf(xv, w2.y, h[rt][9]);
      h[rt][10] = fmaf(xv, w2.z, h[rt][10]); h[rt][11] = fmaf(xv, w2.w, h[rt][11]);
      h[rt][12] = fmaf(xv, w3.x, h[rt][12]); h[rt][13] = fmaf(xv, w3.y, h[rt][13]);
      h[rt][14] = fmaf(xv, w3.z, h[rt][14]); h[rt][15] = fmaf(xv, w3.w, h[rt][15]);
    }
  }

  // ---- per-rt: h2 reduce (pre-scaled by -0.5) + f16-hi A fragments ----
  f16x8 ah0_0, ah1_0; float nhb_0[4];
  f16x8 ah0_1, ah1_1; float nhb_1[4];

#define SPLIT_RT(RTI, AH0, AH1, NHB) do {                                   \
    float ptl = 0.f;                                                        \
    _Pragma("unroll") for (int i = 0; i < 8; ++i) {                         \
      ptl = fmaf(h[RTI][i], h[RTI][i], ptl);                                \
      ptl = fmaf(h[RTI][8 + i], h[RTI][8 + i], ptl);                        \
    }                                                                       \
    ptl += __shfl_xor(ptl, 16);                                             \
    ptl += __shfl_xor(ptl, 32);                                             \
    ptl *= -0.5f;                                                           \
    _Pragma("unroll") for (int r = 0; r < 4; ++r)                           \
      NHB[r] = __shfl(ptl, g * 4 + r);                                      \
    _Pragma("unroll") for (int i = 0; i < 8; ++i) {                         \
      AH0[i] = (_Float16)h[RTI][i];                                         \
      AH1[i] = (_Float16)h[RTI][8 + i];                                     \
    }                                                                       \
  } while (0)

  SPLIT_RT(0, ah0_0, ah1_0, nhb_0);
  SPLIT_RT(1, ah0_1, ah1_1, nhb_1);
#undef SPLIT_RT

  __syncthreads();   // LDS stage complete

  // ---- loop-invariant LDS addressing (sw = (t*16+col)&7 = col&7) ----
  const int sw  = col & 7;
  const _Float16* base0 = s_cent + col * 64 + ((g) ^ sw) * 8;       // chunk a
  const _Float16* base1 = s_cent + col * 64 + ((4 + g) ^ sw) * 8;   // chunk b
  const float* pc2 = s_pre + col;          // c2[t*16+col] at +t*64B (LDS)
  const float* pcw = s_pre + NCLUST + col; // cw[...]

  float ss_0[4] = {0.f, 0.f, 0.f, 0.f}, ww_0[4] = {0.f, 0.f, 0.f, 0.f};
  float ss_1[4] = {0.f, 0.f, 0.f, 0.f}, ww_1[4] = {0.f, 0.f, 0.f, 0.f};

#pragma unroll 2
  for (int t = 0; t < 16; ++t) {
    const f16x8 bh0 = *(const f16x8*)(base0 + t * 1024);   // 16 clusters*64 halves
    const f16x8 bh1 = *(const f16x8*)(base1 + t * 1024);
    const float c2c = pc2[t * 16];
    const float cwc = pcw[t * 16];

#define DO_RT(AH0, AH1, NHB, SS, WW) do {                                   \
    f32x4 hh;                                                               \
    hh[0] = fmaf(-0.5f, c2c, NHB[0]);                                       \
    hh[1] = fmaf(-0.5f, c2c, NHB[1]);                                       \
    hh[2] = fmaf(-0.5f, c2c, NHB[2]);                                       \
    hh[3] = fmaf(-0.5f, c2c, NHB[3]);                                       \
    hh = __builtin_amdgcn_mfma_f32_16x16x32_f16(AH0, bh0, hh, 0, 0, 0);     \
    hh = __builtin_amdgcn_mfma_f32_16x16x32_f16(AH1, bh1, hh, 0, 0, 0);     \
    _Pragma("unroll") for (int r = 0; r < 4; ++r) {                         \
      const float m = hh[r];                    /* h.c_hi - (h2+c2)/2 */    \
      const float d2s = fmaxf(m * KNEG2K, 0.f); /* (dist*log2e)^2 */        \
      const float dsc = __builtin_amdgcn_sqrtf(d2s);   /* v_sqrt_f32 */     \
      const float e = __builtin_amdgcn_exp2f(-dsc);    /* v_exp_f32 */      \
      SS[r] += e;                                                           \
      WW[r] = fmaf(e, cwc, WW[r]);                                          \
    }                                                                       \
  } while (0)

    DO_RT(ah0_0, ah1_0, nhb_0, ss_0, ww_0);
    DO_RT(ah0_1, ah1_1, nhb_1, ss_1, ww_1);
#undef DO_RT
  }

  // ---- reduce over the 16 cluster-lanes, store 32 tokens per wave ----
  const float b2v = b2[0];
#define STORE_RT(RTI, SS, WW) do {                                          \
    _Pragma("unroll") for (int r = 0; r < 4; ++r) {                         \
      float s = SS[r], w = WW[r];                                           \
      s += __shfl_xor(s, 1); w += __shfl_xor(w, 1);                         \
      s += __shfl_xor(s, 2); w += __shfl_xor(w, 2);                         \
      s += __shfl_xor(s, 4); w += __shfl_xor(w, 4);                         \
      s += __shfl_xor(s, 8); w += __shfl_xor(w, 8);                         \
      if (col == 0)                                                         \
        out[tokBase + (RTI) * 16 + g * 4 + r] =                             \
            w * __builtin_amdgcn_rcpf(s) * 0.125f + b2v;                    \
    }                                                                       \
  } while (0)

  STORE_RT(0, ss_0, ww_0);
  STORE_RT(1, ss_1, ww_1);
#undef STORE_RT
}

extern "C" void kernel_launch(void* const* d_in, const int* in_sizes, int n_in,
                              void* d_out, int out_size, void* d_ws, size_t ws_size,
                              hipStream_t stream) {
  const float* x         = (const float*)d_in[0];
  const float* W_embed   = (const float*)d_in[1];
  const float* b_embed   = (const float*)d_in[2];
  const float* emb_table = (const float*)d_in[3];
  const float* centroids = (const float*)d_in[4];
  const float* W2        = (const float*)d_in[5];
  const float* b2        = (const float*)d_in[6];
  float* out = (float*)d_out;

  float* pre = (float*)d_ws;                               // 512 floats
  _Float16* cent_hswz = (_Float16*)((char*)d_ws + 2048);   // 256*64 f16

  precompute_kernel<<<1, NCLUST, 0, stream>>>(centroids, W2, pre);
  split_kernel<<<(NCLUST * 8) / 256, 256, 0, stream>>>(centroids, cent_hswz);
  const int tokPerBlk = 4 * 16 * RT;  // 128
  main_kernel<<<NTOK / tokPerBlk, BLK, 32768 + 2048, stream>>>(
      x, W_embed, b_embed, emb_table, b2, pre, cent_hswz, out);
}